// Round 10
// baseline (12299.096 us; speedup 1.0000x reference)
//
#include <hip/hip_runtime.h>

// ============================================================================
// 8-layer alternating-direction masked LSTM stack + embed + dense/softmax.
// R10 = R9 weight scheme (kk0-3 AGPR-parked regs / kk4-5 LDS / kk6-7 streamed
// one step ahead, lgkm-only barriers) with ROW-SPLIT + GATE REDISTRIBUTION:
//  - grid 8 blocks x 8 batch rows (MFMA/LDS/stream per block unchanged;
//    A-tile rows 8-15 zero),
//  - z redistributed via 16KB LDS zbuf so all 512 threads compute 4 h-slots
//    (vs 8) -> gate-phase VALU halves, no idle lanes,
//  - zbuf holds one column-half; gates run as two half-passes (4 lgkm-only
//    barriers/step), wave w owns gate-row w (wave-uniform mask).
// ============================================================================

typedef _Float16 f16;
typedef _Float16 f16x8 __attribute__((ext_vector_type(8)));
typedef _Float16 f16x4 __attribute__((ext_vector_type(4)));
typedef float    f32x4 __attribute__((ext_vector_type(4)));
typedef float    f32x2 __attribute__((ext_vector_type(2)));

#define DEVI static __device__ __forceinline__

DEVI float fast_sigmoid(float x) {
  return __builtin_amdgcn_rcpf(1.f + __builtin_amdgcn_exp2f(-1.44269504f * x));
}
DEVI float fast_tanh(float x) {
  return 1.f - 2.f * __builtin_amdgcn_rcpf(1.f + __builtin_amdgcn_exp2f(2.88539008f * x));
}
// wave w owns coltiles {2w, 2w+1}; its 8 ntiles: quadrant q=j2>>1 (i,f,c,o),
// parity p=j2&1:  ntg = q*16 + 2w + p
DEVI int ntg_of(int w, int j2) { return ((j2 >> 1) << 4) + 2 * w + (j2 & 1); }

// ---------------------------------------------------------------------------
// pack_frags: dst frag layout [L][kk][nt][lane][8 f16].
// B-frag (16x16x32): lane l holds B[k=kk*32+(l>>4)*8+e][col=nt*16+(l&15)]
// ---------------------------------------------------------------------------
__global__ void pack_frags(const float* __restrict__ src, f16* __restrict__ dst, int nct) {
  const int idx  = blockIdx.x * 256 + threadIdx.x;
  const int lane = idx & 63;
  const int f    = idx >> 6;
  const int nt   = f % nct;
  const int g2   = f / nct;
  const int kk   = g2 & 7;
  const int L    = g2 >> 3;
  const int ncols = nct * 16;
  const float* s = src + (size_t)(L * 256 + kk * 32 + (lane >> 4) * 8) * ncols + nt * 16 + (lane & 15);
  f16x8 v;
#pragma unroll
  for (int e = 0; e < 8; ++e) v[e] = (f16)s[(size_t)e * ncols];
  *(f16x8*)(dst + (size_t)idx * 8) = v;
}

// ---------------------------------------------------------------------------
__global__ void embed_k(const int* __restrict__ wid, const int* __restrict__ pid,
                        const float* __restrict__ emb1, const float* __restrict__ emb2,
                        f16* __restrict__ X) {
  const int r = blockIdx.x;
  const int d = threadIdx.x;                 // 0..127
  const int wv = wid[r], pv = pid[r];
  X[r * 256 + d]       = (f16)emb1[wv * 128 + d];
  X[r * 256 + 128 + d] = (f16)emb2[pv * 128 + d];
}

// ---------------------------------------------------------------------------
__global__ void make_input(const f16* __restrict__ a, const f16* __restrict__ b,
                           f16* __restrict__ X) {
  const size_t q = ((size_t)blockIdx.x * 256 + threadIdx.x) * 8;
  const f16x8 va = *(const f16x8*)(a + q);
  const f16x8 vb = *(const f16x8*)(b + q);
  *(f16x8*)(X + q) = va + vb;
}

// ---------------------------------------------------------------------------
// gemm_xw: xWp = pack(X[16384][256] @ Wi + bias)  (f16)
// packed store: xWp[row][hcol*4 + q], actual gate col = q*256 + hcol
// ---------------------------------------------------------------------------
__global__ __launch_bounds__(512, 2) void gemm_xw(const f16* __restrict__ X,
                                                  const f16* __restrict__ wipf,
                                                  const float* __restrict__ bias,
                                                  f16* __restrict__ xWp) {
  extern __shared__ char smem[];  // 65536 B : A tile [128][256] f16, swizzled
  const int tid = threadIdx.x, lane = tid & 63, w = tid >> 6;
  const int nb = blockIdx.x, mb = blockIdx.y;
  const char* xbase = (const char*)X + (size_t)mb * 128 * 512;
#pragma unroll
  for (int i = 0; i < 8; ++i) {
    const int row = i * 16 + (tid >> 5);
    const int c16 = tid & 31;
    const uint4 v = *(const uint4*)(xbase + row * 512 + c16 * 16);
    *(uint4*)(smem + row * 512 + ((c16 ^ (row & 7)) << 4)) = v;
  }
  __syncthreads();

  const int mh = w >> 2, nw = w & 3;
  const char* wipf_c = (const char*)wipf;
  const float vb0 = bias[nb * 128 + nw * 32 + (lane & 15)];
  const float vb1 = bias[nb * 128 + nw * 32 + 16 + (lane & 15)];
  f32x4 acc[4][2] = {};
#pragma unroll
  for (int kk = 0; kk < 8; ++kk) {
    const f16x8 b0 = *(const f16x8*)(wipf_c + ((size_t)(kk * 64 + nb * 8 + nw * 2 + 0) << 10) + (lane << 4));
    const f16x8 b1 = *(const f16x8*)(wipf_c + ((size_t)(kk * 64 + nb * 8 + nw * 2 + 1) << 10) + (lane << 4));
#pragma unroll
    for (int m2 = 0; m2 < 4; ++m2) {
      const int row = mh * 64 + m2 * 16 + (lane & 15);
      const f16x8 a = *(const f16x8*)(smem + row * 512 + (((kk * 4 + (lane >> 4)) ^ (row & 7)) << 4));
      acc[m2][0] = __builtin_amdgcn_mfma_f32_16x16x32_f16(a, b0, acc[m2][0], 0, 0, 0);
      acc[m2][1] = __builtin_amdgcn_mfma_f32_16x16x32_f16(a, b1, acc[m2][1], 0, 0, 0);
    }
  }
#pragma unroll
  for (int m2 = 0; m2 < 4; ++m2)
#pragma unroll
    for (int n2 = 0; n2 < 2; ++n2)
#pragma unroll
      for (int j = 0; j < 4; ++j) {
        const int r   = mb * 128 + mh * 64 + m2 * 16 + (lane >> 4) * 4 + j;
        const int col = nb * 128 + nw * 32 + n2 * 16 + (lane & 15);
        xWp[(size_t)r * 1024 + (col & 255) * 4 + (col >> 8)] =
            (f16)(acc[m2][n2][j] + (n2 ? vb1 : vb0));
      }
}

// ---------------------------------------------------------------------------
// lstm_layer: 8 blocks x 8 batch rows, full 256 h-cols, 512 thr (8 waves).
// MFMA identical to R9 (A rows 8-15 zero). Gates redistributed via zbuf:
// wave w = gate-row w; thread slot cols {gc, gc+1} x {half0, half1}.
// ---------------------------------------------------------------------------
__global__ __launch_bounds__(512, 2) void lstm_layer(
    const f16*  __restrict__ xWp,   // packed [16384][1024] f16 (bias folded)
    const int*  __restrict__ wid,   // [64][256]
    const f16*  __restrict__ whp,   // layer frag slab: (kk*64+nt)*512 + lane*8
    f16* __restrict__ out,          // [64][256][256] f16
    int reverse) {
  extern __shared__ char smem[];
  // layout: 131072 wh(kk4,5) | 8448 hbuf[16][264] | 16384 zbuf[8][4][128] | 1024 mask
  f16*      hbuf  = (f16*)(smem + 131072);
  float*    zbuf  = (float*)(smem + 131072 + 8448);
  unsigned* mask8 = (unsigned*)(smem + 131072 + 8448 + 16384);
  const int tid  = threadIdx.x;
  const int lane = tid & 63, w = tid >> 6;
  const int g    = blockIdx.x;                 // rows [8g, 8g+8)
  const int r0   = lane & 15, rg = lane >> 4;
  const char* whp_c = (const char*)whp;
  // gate-phase mapping: wave w <-> gate-row w; lane -> 2 cols per half
  const int gr = w;
  const int gc = lane * 2;                     // local col 0..126 (step 2)
  const size_t growbase = ((size_t)(g * 8 + gr)) << 8;

  // stage Wh kk4,kk5 -> LDS
  {
    const char* src = whp_c + (4 << 16);
#pragma unroll
    for (int i = 0; i < 16; ++i) {
      const int off = i * 8192 + tid * 16;
      *(uint4*)(smem + off) = *(const uint4*)(src + off);
    }
  }
  // zero hbuf (rows 8-15 stay zero forever)
  for (int i = tid; i < 16 * 264; i += 512) hbuf[i] = (f16)0.f;
  // packed masks: bit j of mask8[t] = (wid[g*8+j][t] != 0)
  if (tid < 256) {
    unsigned m = 0;
#pragma unroll
    for (int j = 0; j < 8; ++j)
      m |= (wid[((g * 8 + j) << 8) + tid] != 0) ? (1u << j) : 0u;
    mask8[tid] = m;
  }

  // persistent Wh kk0..3 (32 frags = 128 regs; compiler parks in AGPRs)
  f16x8 regB[32];
#pragma unroll
  for (int kk = 0; kk < 4; ++kk)
#pragma unroll
    for (int j2 = 0; j2 < 8; ++j2)
      regB[kk * 8 + j2] = *(const f16x8*)(whp_c + ((size_t)(kk * 64 + ntg_of(w, j2)) << 10) + (lane << 4));

  // stream landing for kk6/kk7 (one step ahead; prologue = step 0)
  f16x8 sb6[8], sb7[8];
#pragma unroll
  for (int j2 = 0; j2 < 8; ++j2) {
    sb6[j2] = *(const f16x8*)(whp_c + ((size_t)(6 * 64 + ntg_of(w, j2)) << 10) + (lane << 4));
    sb7[j2] = *(const f16x8*)(whp_c + ((size_t)(7 * 64 + ntg_of(w, j2)) << 10) + (lane << 4));
  }

  float c[4] = {0.f, 0.f, 0.f, 0.f}, hprev[4] = {0.f, 0.f, 0.f, 0.f};

  __syncthreads();

#pragma unroll 1
  for (int k = 0; k < 256; ++k) {
    const int t_in = reverse ? (255 - k) : k;

    // 1) xW loads for this thread's 4 gate slots (consumed post-BAR1/BAR3)
    const f16* xrow = xWp + (growbase + t_in) * 1024;
    const f16x8 xw0 = *(const f16x8*)(xrow + gc * 4);           // cols gc,gc+1
    const f16x8 xw1 = *(const f16x8*)(xrow + (128 + gc) * 4);   // cols 128+gc,+1

    // 2) MFMA kk0-3 (AGPR), kk4-5 (LDS), kk6-7 (streamed last step)
    f32x4 acc[8] = {};
#pragma unroll
    for (int kk = 0; kk < 4; ++kk) {
      const f16x8 a = *(const f16x8*)&hbuf[r0 * 264 + kk * 32 + rg * 8];
#pragma unroll
      for (int j2 = 0; j2 < 8; ++j2)
        acc[j2] = __builtin_amdgcn_mfma_f32_16x16x32_f16(a, regB[kk * 8 + j2], acc[j2], 0, 0, 0);
    }
#pragma unroll
    for (int kk = 4; kk < 6; ++kk) {
      const f16x8 a = *(const f16x8*)&hbuf[r0 * 264 + kk * 32 + rg * 8];
#pragma unroll
      for (int j2 = 0; j2 < 8; ++j2) {
        const f16x8 b8 = *(const f16x8*)(smem + ((size_t)((kk - 4) * 64 + ntg_of(w, j2)) << 10) + (lane << 4));
        acc[j2] = __builtin_amdgcn_mfma_f32_16x16x32_f16(a, b8, acc[j2], 0, 0, 0);
      }
    }
    {
      const f16x8 a6 = *(const f16x8*)&hbuf[r0 * 264 + 6 * 32 + rg * 8];
#pragma unroll
      for (int j2 = 0; j2 < 8; ++j2)
        acc[j2] = __builtin_amdgcn_mfma_f32_16x16x32_f16(a6, sb6[j2], acc[j2], 0, 0, 0);
      const f16x8 a7 = *(const f16x8*)&hbuf[r0 * 264 + 7 * 32 + rg * 8];
#pragma unroll
      for (int j2 = 0; j2 < 8; ++j2)
        acc[j2] = __builtin_amdgcn_mfma_f32_16x16x32_f16(a7, sb7[j2], acc[j2], 0, 0, 0);
    }

    // 3) reissue next step's kk6-7 stream (R9-proven; pinned placement)
    __builtin_amdgcn_sched_barrier(0);
#pragma unroll
    for (int j2 = 0; j2 < 8; ++j2) {
      sb6[j2] = *(const f16x8*)(whp_c + ((size_t)(6 * 64 + ntg_of(w, j2)) << 10) + (lane << 4));
      sb7[j2] = *(const f16x8*)(whp_c + ((size_t)(7 * 64 + ntg_of(w, j2)) << 10) + (lane << 4));
    }
    __builtin_amdgcn_sched_barrier(0);

    const unsigned mw = mask8[t_in];
    const bool mk = ((mw >> gr) & 1u) != 0u;

    // 4) zbuf write half-0 (waves 0-3 own cols 0-127; real rows need rg<2)
    if (w < 4 && rg < 2) {
#pragma unroll
      for (int j2 = 0; j2 < 8; ++j2) {
        const int q = j2 >> 1, p = j2 & 1;
        const int col = (w & 3) * 32 + p * 16 + r0;
#pragma unroll
        for (int j = 0; j < 4; ++j)
          zbuf[((rg * 4 + j) * 4 + q) * 128 + col] = acc[j2][j];
      }
    }
    __builtin_amdgcn_sched_barrier(0);
    asm volatile("s_waitcnt lgkmcnt(0)\n\ts_barrier" ::: "memory");
    __builtin_amdgcn_sched_barrier(0);

    // 5) gates half-0 (cols gc,gc+1) + publish
    {
      f32x2 zq[4];
#pragma unroll
      for (int q = 0; q < 4; ++q)
        zq[q] = *(const f32x2*)&zbuf[(gr * 4 + q) * 128 + gc];
#pragma unroll
      for (int jj = 0; jj < 2; ++jj) {
        const float zi = zq[0][jj] + (float)xw0[jj * 4 + 0];
        const float zf = zq[1][jj] + (float)xw0[jj * 4 + 1];
        const float zc = zq[2][jj] + (float)xw0[jj * 4 + 2];
        const float zo = zq[3][jj] + (float)xw0[jj * 4 + 3];
        const float ig = fast_sigmoid(zi);
        const float fg = fast_sigmoid(zf);
        const float og = fast_sigmoid(zo);
        const float cb = fast_tanh(zc);
        const float cn = fg * c[jj] + ig * cb;
        const float hn = og * fast_tanh(cn);
        c[jj]     = mk ? cn : c[jj];
        hprev[jj] = mk ? hn : hprev[jj];
        const f16 hv = (f16)hprev[jj];
        hbuf[gr * 264 + gc + jj] = hv;
        out[((growbase + k) << 8) + gc + jj] = hv;
      }
    }
    __builtin_amdgcn_sched_barrier(0);
    asm volatile("s_waitcnt lgkmcnt(0)\n\ts_barrier" ::: "memory");
    __builtin_amdgcn_sched_barrier(0);

    // 6) zbuf write half-1 (waves 4-7 own cols 128-255)
    if (w >= 4 && rg < 2) {
#pragma unroll
      for (int j2 = 0; j2 < 8; ++j2) {
        const int q = j2 >> 1, p = j2 & 1;
        const int col = (w & 3) * 32 + p * 16 + r0;
#pragma unroll
        for (int j = 0; j < 4; ++j)
          zbuf[((rg * 4 + j) * 4 + q) * 128 + col] = acc[j2][j];
      }
    }
    __builtin_amdgcn_sched_barrier(0);
    asm volatile("s_waitcnt lgkmcnt(0)\n\ts_barrier" ::: "memory");
    __builtin_amdgcn_sched_barrier(0);

    // 7) gates half-1 (cols 128+gc, 128+gc+1) + publish
    {
      f32x2 zq[4];
#pragma unroll
      for (int q = 0; q < 4; ++q)
        zq[q] = *(const f32x2*)&zbuf[(gr * 4 + q) * 128 + gc];
#pragma unroll
      for (int jj = 0; jj < 2; ++jj) {
        const float zi = zq[0][jj] + (float)xw1[jj * 4 + 0];
        const float zf = zq[1][jj] + (float)xw1[jj * 4 + 1];
        const float zc = zq[2][jj] + (float)xw1[jj * 4 + 2];
        const float zo = zq[3][jj] + (float)xw1[jj * 4 + 3];
        const float ig = fast_sigmoid(zi);
        const float fg = fast_sigmoid(zf);
        const float og = fast_sigmoid(zo);
        const float cb = fast_tanh(zc);
        const float cn = fg * c[2 + jj] + ig * cb;
        const float hn = og * fast_tanh(cn);
        c[2 + jj]     = mk ? cn : c[2 + jj];
        hprev[2 + jj] = mk ? hn : hprev[2 + jj];
        const f16 hv = (f16)hprev[2 + jj];
        hbuf[gr * 264 + 128 + gc + jj] = hv;
        out[((growbase + k) << 8) + 128 + gc + jj] = hv;
      }
    }
    // 8) end-of-step barrier (orders h publishes + zbuf half-0 reuse)
    __builtin_amdgcn_sched_barrier(0);
    asm volatile("s_waitcnt lgkmcnt(0)\n\ts_barrier" ::: "memory");
    __builtin_amdgcn_sched_barrier(0);
  }
}

// ---------------------------------------------------------------------------
// final: softmax((o6+o7) @ Wd + bd) -> f32 out [16384][128]   (o* are f16)
// ---------------------------------------------------------------------------
__global__ __launch_bounds__(512, 2) void final_k(const f16* __restrict__ o0,
                                                  const f16* __restrict__ o1,
                                                  const f16* __restrict__ wdpf,
                                                  const float* __restrict__ bd,
                                                  float* __restrict__ outp) {
  const int tid = threadIdx.x, lane = tid & 63, w = tid >> 6;
  const int rbase = blockIdx.x * 128 + w * 16;
  const char* wdpf_c = (const char*)wdpf;

  f32x4 acc[8] = {};
#pragma unroll
  for (int kk = 0; kk < 8; ++kk) {
    const int r  = rbase + (lane & 15);
    const int k0 = kk * 32 + (lane >> 4) * 8;
    const f16x8 x = *(const f16x8*)(o0 + (size_t)r * 256 + k0);
    const f16x8 y = *(const f16x8*)(o1 + (size_t)r * 256 + k0);
    const f16x8 a = x + y;
#pragma unroll
    for (int nt = 0; nt < 8; ++nt) {
      const f16x8 b = *(const f16x8*)(wdpf_c + ((size_t)(kk * 8 + nt) << 10) + (lane << 4));
      acc[nt] = __builtin_amdgcn_mfma_f32_16x16x32_f16(a, b, acc[nt], 0, 0, 0);
    }
  }

  float vb[8];
#pragma unroll
  for (int nt = 0; nt < 8; ++nt) vb[nt] = bd[nt * 16 + (lane & 15)];

#pragma unroll
  for (int j = 0; j < 4; ++j) {
    float v[8];
#pragma unroll
    for (int nt = 0; nt < 8; ++nt) v[nt] = acc[nt][j] + vb[nt];
    float mx = v[0];
#pragma unroll
    for (int nt = 1; nt < 8; ++nt) mx = fmaxf(mx, v[nt]);
#pragma unroll
    for (int m = 1; m < 16; m <<= 1) mx = fmaxf(mx, __shfl_xor(mx, m, 64));
    float s = 0.f;
#pragma unroll
    for (int nt = 0; nt < 8; ++nt) {
      v[nt] = __builtin_amdgcn_exp2f(1.44269504f * (v[nt] - mx));
      s += v[nt];
    }
#pragma unroll
    for (int m = 1; m < 16; m <<= 1) s += __shfl_xor(s, m, 64);
    const float rs = __builtin_amdgcn_rcpf(s);
    const int r = rbase + (lane >> 4) * 4 + j;
#pragma unroll
    for (int nt = 0; nt < 8; ++nt)
      outp[(size_t)r * 128 + nt * 16 + (lane & 15)] = v[nt] * rs;
  }
}

// ---------------------------------------------------------------------------
extern "C" void kernel_launch(void* const* d_in, const int* in_sizes, int n_in,
                              void* d_out, int out_size, void* d_ws, size_t ws_size,
                              hipStream_t stream) {
  const int*   wid  = (const int*)d_in[0];
  const int*   pid  = (const int*)d_in[1];
  const float* emb1 = (const float*)d_in[2];
  const float* emb2 = (const float*)d_in[3];
  const float* Wis  = (const float*)d_in[4];
  const float* Whs  = (const float*)d_in[5];
  const float* bs   = (const float*)d_in[6];
  const float* Wd   = (const float*)d_in[7];
  const float* bd   = (const float*)d_in[8];

  char* ws = (char*)d_ws;
  f16* Whp  = (f16*)(ws + 0);          //  4,194,304
  f16* Wipf = (f16*)(ws + 4194304);    //  4,194,304
  f16* Wdpf = (f16*)(ws + 8388608);    //     65,536
  f16* X    = (f16*)(ws + 8454144);    //  8,388,608
  f16* xWp  = (f16*)(ws + 16842752);   // 33,554,432
  f16* o0   = (f16*)(ws + 50397184);   //  8,388,608
  f16* o1   = (f16*)(ws + 58785792);   //  8,388,608

  hipFuncSetAttribute((const void*)gemm_xw,    hipFuncAttributeMaxDynamicSharedMemorySize, 65536);
  hipFuncSetAttribute((const void*)lstm_layer, hipFuncAttributeMaxDynamicSharedMemorySize, 156928);

  pack_frags<<<1024, 256, 0, stream>>>(Whs, Whp, 64);
  pack_frags<<<1024, 256, 0, stream>>>(Wis, Wipf, 64);
  pack_frags<<<16,   256, 0, stream>>>(Wd,  Wdpf, 8);
  embed_k<<<16384, 128, 0, stream>>>(wid, pid, emb1, emb2, X);

  f16* obuf[2] = {o0, o1};
  for (int L = 0; L < 8; ++L) {
    const f16* xin = X;
    if (L == 1) {
      xin = o0;                                   // identity input, same layout
    } else if (L >= 2) {
      make_input<<<2048, 256, 0, stream>>>(obuf[L & 1], obuf[(L - 1) & 1], X);
    }
    gemm_xw<<<dim3(8, 128), 512, 65536, stream>>>(xin, Wipf + (size_t)L * 262144,
                                                  bs + L * 1024, xWp);
    lstm_layer<<<8, 512, 156928, stream>>>(xWp, wid, Whp + (size_t)L * 262144,
                                           obuf[L & 1], L & 1);
  }
  final_k<<<128, 512, 0, stream>>>(o0, o1, Wdpf, bd, (float*)d_out);
}